// Round 2
// baseline (623.572 us; speedup 1.0000x reference)
//
#include <hip/hip_runtime.h>

// Fused 16-expert, 2-layer Linear+ReLU stack — round 2.
// Block = 256 thr (4 waves) x TILES=4 tiles of 64 tokens = 256 tokens/block.
// W staged ONCE per layer per block (amortized 4x vs round 1); layer-1
// activations live packed-bf16 in registers across the W1 re-stage; the
// C/D->A layout round-trip through sY is wave-private => no barriers in
// pass A or pass B, only 3 per block total.

#define NF   128
#define NM   16
#define NTOK 524288
#define TPM  (NTOK / NM)           // 32768 tokens per model
#define BM   64                    // tokens per tile
#define TILES 4                    // tiles per block
#define BLK_PER_M (TPM / (BM * TILES))   // 128
#define WPAD 136                   // bf16 row pitch: 272 B, 16-B aligned, bank-spread

typedef __attribute__((ext_vector_type(8))) short bf16x8;
typedef __attribute__((ext_vector_type(4))) float f32x4;

__device__ __forceinline__ unsigned short f2bf(float f) {
    union { float f; unsigned u; } v; v.f = f;
    unsigned r = v.u + 0x7FFFu + ((v.u >> 16) & 1u);   // RNE
    return (unsigned short)(r >> 16);
}
__device__ __forceinline__ unsigned f2bf2(float lo, float hi) {
    return (unsigned)f2bf(lo) | ((unsigned)f2bf(hi) << 16);
}

__global__ __launch_bounds__(256, 3) void mlp16_kernel(
        const float* __restrict__ x, const float* __restrict__ W,
        const float* __restrict__ b, float* __restrict__ out) {
    __shared__ alignas(16) unsigned short sW[NF * WPAD];   // one layer at a time, 34816 B
    __shared__ alignas(16) unsigned short sY[BM * WPAD];   // 17408 B, wave-private rows
    __shared__ float sB[2 * NF];

    const int t    = threadIdx.x;
    const int wave = t >> 6;
    const int lane = t & 63;
    const int ln   = lane & 15;
    const int q    = lane >> 4;

    const int m   = blockIdx.x / BLK_PER_M;
    const int blk = blockIdx.x % BLK_PER_M;
    const size_t row0 = (size_t)m * TPM + (size_t)blk * (BM * TILES);

    sB[t] = b[m * 2 * NF + t];

    const float4* Wm = (const float4*)(W + (size_t)m * 2 * NF * NF);
    // ---- stage W0 (fp32 -> bf16) ----
    #pragma unroll
    for (int i = 0; i < 16; ++i) {
        int c = t + i * 256;
        float4 w = Wm[c];
        unsigned short* d = &sW[(c >> 5) * WPAD + (c & 31) * 4];
        d[0] = f2bf(w.x); d[1] = f2bf(w.y); d[2] = f2bf(w.z); d[3] = f2bf(w.w);
    }
    __syncthreads();

    unsigned ypk[TILES][16];   // layer-1 activations, packed bf16 pairs (r, r+1)

    // ---- pass A: layer 1 over all tiles, barrier-free ----
    #pragma unroll
    for (int tt = 0; tt < TILES; ++tt) {
        f32x4 acc[8];
        #pragma unroll
        for (int g = 0; g < 8; ++g) acc[g] = (f32x4){0.f, 0.f, 0.f, 0.f};

        const float* xrow = x + (row0 + tt * BM + wave * 16 + ln) * NF;
        #pragma unroll
        for (int kt = 0; kt < 4; ++kt) {
            const int f0 = kt * 32 + q * 8;
            float4 a0 = *(const float4*)(xrow + f0);
            float4 a1 = *(const float4*)(xrow + f0 + 4);
            bf16x8 af;
            af[0] = (short)f2bf(a0.x); af[1] = (short)f2bf(a0.y);
            af[2] = (short)f2bf(a0.z); af[3] = (short)f2bf(a0.w);
            af[4] = (short)f2bf(a1.x); af[5] = (short)f2bf(a1.y);
            af[6] = (short)f2bf(a1.z); af[7] = (short)f2bf(a1.w);
            #pragma unroll
            for (int g = 0; g < 8; ++g) {
                bf16x8 bfr = *(const bf16x8*)&sW[(g * 16 + ln) * WPAD + f0];
                acc[g] = __builtin_amdgcn_mfma_f32_16x16x32_bf16(af, bfr, acc[g], 0, 0, 0);
            }
        }
        #pragma unroll
        for (int g = 0; g < 8; ++g) {
            const float bias = sB[g * 16 + ln];
            float v0 = fmaxf(acc[g][0] + bias, 0.f);
            float v1 = fmaxf(acc[g][1] + bias, 0.f);
            float v2 = fmaxf(acc[g][2] + bias, 0.f);
            float v3 = fmaxf(acc[g][3] + bias, 0.f);
            ypk[tt][g * 2]     = f2bf2(v0, v1);
            ypk[tt][g * 2 + 1] = f2bf2(v2, v3);
        }
    }

    __syncthreads();                       // all waves done reading sW0
    // ---- stage W1 over the same buffer ----
    const float4* W1 = Wm + (NF * NF / 4);
    #pragma unroll
    for (int i = 0; i < 16; ++i) {
        int c = t + i * 256;
        float4 w = W1[c];
        unsigned short* d = &sW[(c >> 5) * WPAD + (c & 31) * 4];
        d[0] = f2bf(w.x); d[1] = f2bf(w.y); d[2] = f2bf(w.z); d[3] = f2bf(w.w);
    }
    __syncthreads();

    // ---- pass B: layer 2 over all tiles, barrier-free (sY rows wave-private) ----
    #pragma unroll
    for (int tt = 0; tt < TILES; ++tt) {
        // C/D layout (row = q*4+r, col = g*16+ln) -> row-major sY
        #pragma unroll
        for (int g = 0; g < 8; ++g) {
            #pragma unroll
            for (int p = 0; p < 2; ++p) {
                unsigned d = ypk[tt][g * 2 + p];
                sY[(wave * 16 + q * 4 + 2 * p)     * WPAD + g * 16 + ln] = (unsigned short)(d & 0xFFFFu);
                sY[(wave * 16 + q * 4 + 2 * p + 1) * WPAD + g * 16 + ln] = (unsigned short)(d >> 16);
            }
        }
        f32x4 acc[8];
        #pragma unroll
        for (int g = 0; g < 8; ++g) acc[g] = (f32x4){0.f, 0.f, 0.f, 0.f};

        const unsigned short* yrow = &sY[(wave * 16 + ln) * WPAD];
        #pragma unroll
        for (int kt = 0; kt < 4; ++kt) {
            const int f0 = kt * 32 + q * 8;
            bf16x8 af = *(const bf16x8*)(yrow + f0);
            #pragma unroll
            for (int g = 0; g < 8; ++g) {
                bf16x8 bfr = *(const bf16x8*)&sW[(g * 16 + ln) * WPAD + f0];
                acc[g] = __builtin_amdgcn_mfma_f32_16x16x32_bf16(af, bfr, acc[g], 0, 0, 0);
            }
        }
        float* orow = out + (row0 + tt * BM + wave * 16) * NF;
        #pragma unroll
        for (int g = 0; g < 8; ++g) {
            const float bias = sB[NF + g * 16 + ln];
            #pragma unroll
            for (int r = 0; r < 4; ++r) {
                float v = fmaxf(acc[g][r] + bias, 0.f);
                orow[(size_t)(q * 4 + r) * NF + g * 16 + ln] = v;
            }
        }
    }
}

extern "C" void kernel_launch(void* const* d_in, const int* in_sizes, int n_in,
                              void* d_out, int out_size, void* d_ws, size_t ws_size,
                              hipStream_t stream) {
    const float* x = (const float*)d_in[0];
    const float* W = (const float*)d_in[1];
    const float* b = (const float*)d_in[2];
    float* out = (float*)d_out;
    mlp16_kernel<<<dim3(NM * BLK_PER_M), dim3(256), 0, stream>>>(x, W, b, out);
}